// Round 1
// baseline (751.855 us; speedup 1.0000x reference)
//
#include <hip/hip_runtime.h>

#define NUM_DOCS 1000000
#define VOCAB 30522
#define NNZ 64000000LL
#define Q_NNZ 32
#define TOP_K 100
#define CAND_MAX 4096
#define BM_WORDS 954   // ceil(30522/32)

// ---- workspace layout (units of 4 bytes) ----
#define OFF_Q       0                        // dense query, 30528 floats
#define OFF_HIST    30528                    // 65536 uints
#define OFF_COUNTER (OFF_HIST + 65536)       // 1 uint (padded to 16)
#define OFF_THRESH  (OFF_COUNTER + 1)        // 1 uint
#define OFF_CANDS   (OFF_COUNTER + 16)       // CAND_MAX floats
#define OFF_CANDI   (OFF_CANDS + CAND_MAX)   // CAND_MAX ints
#define OFF_SCORES  (OFF_CANDI + CAND_MAX)   // NUM_DOCS floats
#define ZERO_WORDS  (OFF_COUNTER + 16)       // region that must be zeroed each launch

// Build dense query (duplicates coalesced by atomic add).
__global__ void scatter_q_kernel(const float* __restrict__ qv, const int* __restrict__ qi,
                                 float* __restrict__ q) {
    int i = threadIdx.x;
    if (i < Q_NNZ) atomicAdd(&q[qi[i]], qv[i]);
}

// Per-doc scores. 4 threads/doc, 16 nnz/thread, float4/int4 streaming loads.
// Query membership via 4KB LDS bitmap; value fetched from global dense q only on hit (~0.1%).
__global__ void score_kernel(const float* __restrict__ dv, const int* __restrict__ di,
                             const int* __restrict__ qi, const float* __restrict__ qg,
                             float* __restrict__ scores) {
    __shared__ unsigned bm[BM_WORDS];
    for (int i = threadIdx.x; i < BM_WORDS; i += blockDim.x) bm[i] = 0u;
    __syncthreads();
    if (threadIdx.x < Q_NNZ) {
        int v = qi[threadIdx.x];
        atomicOr(&bm[v >> 5], 1u << (v & 31));
    }
    __syncthreads();

    long long t = (long long)blockIdx.x * blockDim.x + threadIdx.x;   // 0 .. NNZ/16
    long long base = t * 16;
    const float4* dv4 = (const float4*)(dv + base);
    const int4*   di4 = (const int4*)(di + base);
    float sum = 0.f;
#pragma unroll
    for (int j = 0; j < 4; ++j) {
        float4 v = dv4[j];
        int4   x = di4[j];
        if ((bm[x.x >> 5] >> (x.x & 31)) & 1u) sum += v.x * qg[x.x];
        if ((bm[x.y >> 5] >> (x.y & 31)) & 1u) sum += v.y * qg[x.y];
        if ((bm[x.z >> 5] >> (x.z & 31)) & 1u) sum += v.z * qg[x.z];
        if ((bm[x.w >> 5] >> (x.w & 31)) & 1u) sum += v.w * qg[x.w];
    }
    sum += __shfl_xor(sum, 1);
    sum += __shfl_xor(sum, 2);
    if ((t & 3) == 0) scores[t >> 2] = sum;
}

// Histogram of positive scores by top-16 float bits (monotone for positive floats).
__global__ void hist_kernel(const float* __restrict__ scores, unsigned* __restrict__ hist) {
    int i = blockIdx.x * blockDim.x + threadIdx.x;
    if (i < NUM_DOCS) {
        float s = scores[i];
        if (s > 0.f) atomicAdd(&hist[__float_as_uint(s) >> 16], 1u);
    }
}

// Find smallest bin T with suffix count >= TOP_K; threshold bits = T<<16.
__global__ void thresh_kernel(const unsigned* __restrict__ hist, unsigned* __restrict__ thresh) {
    __shared__ unsigned part[256];
    int t = threadIdx.x;
    unsigned s = 0;
    const unsigned* h = hist + t * 256;
    for (int j = 0; j < 256; ++j) s += h[j];
    part[t] = s;
    __syncthreads();
    if (t == 0) {
        unsigned cum = 0;
        int c = 255;
        for (; c >= 0; --c) {
            if (cum + part[c] >= TOP_K) break;
            cum += part[c];
        }
        unsigned bin = 1;  // fallback: fewer than TOP_K positive scores (won't happen here)
        if (c >= 0) {
            int b = c * 256 + 255;
            for (; b >= c * 256; --b) {
                cum += hist[b];
                if (cum >= TOP_K) break;
            }
            if (b < c * 256) b = c * 256;
            bin = (unsigned)b;
        }
        thresh[0] = bin << 16;
    }
}

// Gather candidates >= threshold (count in [TOP_K, TOP_K + hist[T]), typically ~100-200).
__global__ void gather_kernel(const float* __restrict__ scores, const unsigned* __restrict__ thresh,
                              unsigned* __restrict__ counter,
                              float* __restrict__ cs, int* __restrict__ ci) {
    int i = blockIdx.x * blockDim.x + threadIdx.x;
    if (i < NUM_DOCS) {
        float s = scores[i];
        if (__float_as_uint(s) >= thresh[0]) {
            unsigned p = atomicAdd(counter, 1u);
            if (p < CAND_MAX) { cs[p] = s; ci[p] = i; }
        }
    }
}

// Single-wave iterative selection of top-100 (desc score, ties -> lower doc index,
// matching jax top_k stability across the shard-major candidate order).
__global__ void topk_kernel(const unsigned* __restrict__ counter,
                            const float* __restrict__ cs, const int* __restrict__ ci,
                            float* __restrict__ out) {
    __shared__ float ls[CAND_MAX];
    __shared__ int   li[CAND_MAX];
    int n = (int)min(counter[0], (unsigned)CAND_MAX);
    for (int i = threadIdx.x; i < n; i += 64) { ls[i] = cs[i]; li[i] = ci[i]; }
    __syncthreads();
    for (int k = 0; k < TOP_K; ++k) {
        float best = -1.f; int bestd = 0x7fffffff; int bestp = -1;
        for (int i = threadIdx.x; i < n; i += 64) {
            float s = ls[i];
            int   d = li[i];
            if (s > best || (s == best && d < bestd)) { best = s; bestd = d; bestp = i; }
        }
        for (int off = 1; off < 64; off <<= 1) {
            float os = __shfl_xor(best,  off);
            int   od = __shfl_xor(bestd, off);
            int   op = __shfl_xor(bestp, off);
            if (os > best || (os == best && od < bestd)) { best = os; bestd = od; bestp = op; }
        }
        if (threadIdx.x == 0) {
            out[k]         = (bestp >= 0) ? best : 0.f;
            out[TOP_K + k] = (float)((bestp >= 0) ? bestd : 0);
            if (bestp >= 0) ls[bestp] = -1.f;
        }
        __syncthreads();
    }
}

extern "C" void kernel_launch(void* const* d_in, const int* in_sizes, int n_in,
                              void* d_out, int out_size, void* d_ws, size_t ws_size,
                              hipStream_t stream) {
    const float* doc_values  = (const float*)d_in[0];
    const float* q_values    = (const float*)d_in[1];
    const int*   doc_indices = (const int*)d_in[2];
    // d_in[3] = row_ids: implicit (row = nnz/64), never read -> saves 256 MB of HBM traffic
    const int*   q_indices   = (const int*)d_in[4];
    float* out = (float*)d_out;

    float*    ws      = (float*)d_ws;
    float*    q       = ws + OFF_Q;
    unsigned* hist    = (unsigned*)d_ws + OFF_HIST;
    unsigned* counter = (unsigned*)d_ws + OFF_COUNTER;
    unsigned* thresh  = (unsigned*)d_ws + OFF_THRESH;
    float*    cs      = ws + OFF_CANDS;
    int*      ci      = (int*)d_ws + OFF_CANDI;
    float*    scores  = ws + OFF_SCORES;

    // zero query table + histogram + counter (ws is re-poisoned to 0xAA before every launch)
    hipMemsetAsync(d_ws, 0, (size_t)ZERO_WORDS * 4, stream);

    scatter_q_kernel<<<1, 64, 0, stream>>>(q_values, q_indices, q);

    // NNZ/16 threads = 4M -> 15625 blocks of 256
    score_kernel<<<15625, 256, 0, stream>>>(doc_values, doc_indices, q_indices, q, scores);

    int blocks1m = (NUM_DOCS + 255) / 256;
    hist_kernel<<<blocks1m, 256, 0, stream>>>(scores, hist);
    thresh_kernel<<<1, 256, 0, stream>>>(hist, thresh);
    gather_kernel<<<blocks1m, 256, 0, stream>>>(scores, thresh, counter, cs, ci);
    topk_kernel<<<1, 64, 0, stream>>>(counter, cs, ci, out);
}

// Round 3
// 649.026 us; speedup vs baseline: 1.1584x; 1.1584x over previous
//
#include <hip/hip_runtime.h>

#define NUM_DOCS 1000000
#define VOCAB 30522
#define NNZ 64000000LL
#define Q_NNZ 32
#define TOP_K 100
#define CAND_MAX 4096
#define BM_WORDS 954   // ceil(30522/32)

// ---- workspace layout (units of 4 bytes) ----
#define OFF_Q       0                         // dense query, 30528 floats
#define OFF_HIST    30528                     // 65536 uints
#define OFF_PART    (OFF_HIST + 65536)        // 256 uints (per-block hist partials)
#define OFF_DONE    (OFF_PART + 256)          // 1 uint
#define OFF_COUNTER (OFF_DONE + 1)            // 1 uint
#define OFF_THRESH  (OFF_COUNTER + 1)         // 1 uint
#define OFF_CTRLEND (OFF_THRESH + 13)         // pad to 16
#define OFF_CANDS   OFF_CTRLEND               // CAND_MAX floats
#define OFF_CANDI   (OFF_CANDS + CAND_MAX)    // CAND_MAX ints
#define OFF_SCORES  (OFF_CANDI + CAND_MAX)    // NUM_DOCS floats
#define ZERO_WORDS  OFF_CTRLEND               // q + hist + part + counters

// Build dense query (duplicates coalesced by atomic add).
__global__ void scatter_q_kernel(const float* __restrict__ qv, const int* __restrict__ qi,
                                 float* __restrict__ q) {
    int i = threadIdx.x;
    if (i < Q_NNZ) atomicAdd(&q[qi[i]], qv[i]);
}

// Per-doc scores, fused histogram.
// 4 nnz/thread via one coalesced int4; dv loaded ONLY on bitmap hit (~0.1% of nnz),
// so the streamed traffic is just doc_indices (256 MB) instead of 512 MB.
// 16 lanes/doc -> shfl_xor reduce; writer lane also histograms positive scores.
// GRID MUST BE EXACTLY NNZ/4/256 = 62500 blocks (no bounds check in kernel).
__global__ __launch_bounds__(256) void score_kernel(
        const float* __restrict__ dv, const int* __restrict__ di,
        const int* __restrict__ qi, const float* __restrict__ qg,
        float* __restrict__ scores, unsigned* __restrict__ hist) {
    __shared__ unsigned bm[BM_WORDS];
    for (int i = threadIdx.x; i < BM_WORDS; i += 256) bm[i] = 0u;
    __syncthreads();
    if (threadIdx.x < Q_NNZ) {
        int v = qi[threadIdx.x];
        atomicOr(&bm[v >> 5], 1u << (v & 31));
    }
    __syncthreads();

    int t = blockIdx.x * 256 + threadIdx.x;        // 0 .. 16M
    long long base = (long long)t * 4;
    int4 x = *(const int4*)(di + base);
    float s = 0.f;
    if ((bm[x.x >> 5] >> (x.x & 31)) & 1u) s += dv[base + 0] * qg[x.x];
    if ((bm[x.y >> 5] >> (x.y & 31)) & 1u) s += dv[base + 1] * qg[x.y];
    if ((bm[x.z >> 5] >> (x.z & 31)) & 1u) s += dv[base + 2] * qg[x.z];
    if ((bm[x.w >> 5] >> (x.w & 31)) & 1u) s += dv[base + 3] * qg[x.w];
    s += __shfl_xor(s, 1);
    s += __shfl_xor(s, 2);
    s += __shfl_xor(s, 4);
    s += __shfl_xor(s, 8);
    if ((threadIdx.x & 15) == 0) {
        int doc = t >> 4;
        scores[doc] = s;
        if (s > 0.f) atomicAdd(&hist[__float_as_uint(s) >> 16], 1u);
    }
}

// Threshold: 256 blocks each reduce one 256-bin chunk (coalesced); last block
// (atomic done-counter) finds the superbin then scans its 256 bins from LDS.
// part[] is read/written via atomics -> coherent across XCDs.
__global__ __launch_bounds__(256) void thresh_kernel(
        const unsigned* __restrict__ hist, unsigned* __restrict__ part,
        unsigned* __restrict__ done, unsigned* __restrict__ thresh) {
    int b = blockIdx.x, t = threadIdx.x;
    unsigned v = hist[b * 256 + t];
    unsigned s = v;
    for (int off = 1; off < 64; off <<= 1) s += __shfl_xor(s, off);
    __shared__ unsigned wsum[4];
    if ((t & 63) == 0) wsum[t >> 6] = s;
    __syncthreads();
    if (t == 0) {
        atomicAdd(&part[b], wsum[0] + wsum[1] + wsum[2] + wsum[3]);
        __threadfence();
    }
    __shared__ int lastflag;
    if (t == 0) lastflag = (atomicAdd(done, 1u) == 255u) ? 1 : 0;
    __syncthreads();
    if (!lastflag) return;

    // ---- last block: finish ----
    __shared__ unsigned parts[256];
    parts[t] = atomicAdd(&part[t], 0u);   // coherent read
    __syncthreads();
    __shared__ int sc;
    __shared__ unsigned scum;
    if (t == 0) {
        unsigned cum = 0;
        int c = 255;
        for (; c >= 0; --c) {
            if (cum + parts[c] >= TOP_K) break;
            cum += parts[c];
        }
        sc = c; scum = cum;
    }
    __syncthreads();
    int c = sc;
    __shared__ unsigned bins[256];
    if (c >= 0) bins[t] = hist[c * 256 + t];
    __syncthreads();
    if (t == 0) {
        unsigned bin = 1;   // fallback: <TOP_K positive scores
        if (c >= 0) {
            unsigned cum = scum;
            int b2 = 255;
            for (; b2 >= 0; --b2) {
                cum += bins[b2];
                if (cum >= TOP_K) break;
            }
            if (b2 < 0) b2 = 0;
            bin = (unsigned)(c * 256 + b2);
        }
        thresh[0] = bin << 16;
    }
}

// Gather candidates >= threshold (count in [TOP_K, TOP_K + bin population)).
__global__ void gather_kernel(const float* __restrict__ scores, const unsigned* __restrict__ thresh,
                              unsigned* __restrict__ counter,
                              float* __restrict__ cs, int* __restrict__ ci) {
    int i = blockIdx.x * blockDim.x + threadIdx.x;
    if (i < NUM_DOCS) {
        float s = scores[i];
        if (__float_as_uint(s) >= thresh[0]) {
            unsigned p = atomicAdd(counter, 1u);
            if (p < CAND_MAX) { cs[p] = s; ci[p] = i; }
        }
    }
}

// Single-wave iterative top-100 (desc score, ties -> lower doc index).
__global__ void topk_kernel(const unsigned* __restrict__ counter,
                            const float* __restrict__ cs, const int* __restrict__ ci,
                            float* __restrict__ out) {
    __shared__ float ls[CAND_MAX];
    __shared__ int   li[CAND_MAX];
    int n = (int)min(counter[0], (unsigned)CAND_MAX);
    for (int i = threadIdx.x; i < n; i += 64) { ls[i] = cs[i]; li[i] = ci[i]; }
    __syncthreads();
    for (int k = 0; k < TOP_K; ++k) {
        float best = -1.f; int bestd = 0x7fffffff; int bestp = -1;
        for (int i = threadIdx.x; i < n; i += 64) {
            float s = ls[i];
            int   d = li[i];
            if (s > best || (s == best && d < bestd)) { best = s; bestd = d; bestp = i; }
        }
        for (int off = 1; off < 64; off <<= 1) {
            float os = __shfl_xor(best,  off);
            int   od = __shfl_xor(bestd, off);
            int   op = __shfl_xor(bestp, off);
            if (os > best || (os == best && od < bestd)) { best = os; bestd = od; bestp = op; }
        }
        if (threadIdx.x == 0) {
            out[k]         = (bestp >= 0) ? best : 0.f;
            out[TOP_K + k] = (float)((bestp >= 0) ? bestd : 0);
            if (bestp >= 0) ls[bestp] = -1.f;
        }
        __syncthreads();
    }
}

extern "C" void kernel_launch(void* const* d_in, const int* in_sizes, int n_in,
                              void* d_out, int out_size, void* d_ws, size_t ws_size,
                              hipStream_t stream) {
    const float* doc_values  = (const float*)d_in[0];
    const float* q_values    = (const float*)d_in[1];
    const int*   doc_indices = (const int*)d_in[2];
    // d_in[3] = row_ids: implicit (row = nnz/64), never read
    const int*   q_indices   = (const int*)d_in[4];
    float* out = (float*)d_out;

    float*    ws      = (float*)d_ws;
    float*    q       = ws + OFF_Q;
    unsigned* hist    = (unsigned*)d_ws + OFF_HIST;
    unsigned* part    = (unsigned*)d_ws + OFF_PART;
    unsigned* done    = (unsigned*)d_ws + OFF_DONE;
    unsigned* counter = (unsigned*)d_ws + OFF_COUNTER;
    unsigned* thresh  = (unsigned*)d_ws + OFF_THRESH;
    float*    cs      = ws + OFF_CANDS;
    int*      ci      = (int*)d_ws + OFF_CANDI;
    float*    scores  = ws + OFF_SCORES;

    // zero query table + histogram + partials + counters (ws re-poisoned each launch)
    hipMemsetAsync(d_ws, 0, (size_t)ZERO_WORDS * 4, stream);

    scatter_q_kernel<<<1, 64, 0, stream>>>(q_values, q_indices, q);

    // NNZ/4 threads = 16M -> EXACTLY 62500 blocks of 256; fused score + histogram
    score_kernel<<<62500, 256, 0, stream>>>(doc_values, doc_indices, q_indices, q, scores, hist);

    thresh_kernel<<<256, 256, 0, stream>>>(hist, part, done, thresh);

    int blocks1m = (NUM_DOCS + 255) / 256;
    gather_kernel<<<blocks1m, 256, 0, stream>>>(scores, thresh, counter, cs, ci);
    topk_kernel<<<1, 64, 0, stream>>>(counter, cs, ci, out);
}